// Round 10
// baseline (211.258 us; speedup 1.0000x reference)
//
#include <hip/hip_runtime.h>
#include <math.h>

typedef float f32x4 __attribute__((ext_vector_type(4)));
typedef float f32x2 __attribute__((ext_vector_type(2)));
typedef int   i32x4 __attribute__((ext_vector_type(4)));

// RBF constants: means = linspace(exp(-5), 1, 128); beta = (2/128*(1-exp(-5)))^-2
#define RBF_START 0.006737946999085467f
#define RBF_H     (0.993262053000915f / 127.0f)
#define RBF_INVH  (127.0f / 0.993262053000915f)
#define RBF_BETA  (1.0f / ((2.0f/128.0f*0.993262053000915f) * (2.0f/128.0f*0.993262053000915f)))
#define KN 256          // knots: KN+1 samples of e in [0,1]; lerp err ~1e-6 on bias

// ---------------- kernel A: grid 257. Block g: bias-table knot g; blocks 0..255 also
// compute padding mask for rows 8g..8g+7. Total wg 2305 -> 257.
__global__ __launch_bounds__(256) void prep_kernel(
    const float* __restrict__ nf, int* __restrict__ mask,
    const float* __restrict__ w1, const float* __restrict__ b1,
    const float* __restrict__ w2, const float* __restrict__ b2,
    float* __restrict__ tableG) {
  int g = blockIdx.x, t = threadIdx.x;
  __shared__ float ef_s[128];
  __shared__ float hid_s[128];
  __shared__ int wany[8][4];

  // ---- table knot g ----
  float e = (float)g * (1.0f / (float)KN);
  if (t < 128) {
    float mu = fmaf((float)t, RBF_H, RBF_START);
    float diff = e - mu;
    ef_s[t] = __expf(-RBF_BETA * diff * diff);
  }
  __syncthreads();
  if (t < 128) {
    float s = b1[t];
    for (int k = 0; k < 128; k++) s = fmaf(ef_s[k], w1[k * 128 + t], s);
    hid_s[t] = 0.5f * s * (1.0f + erff(s * 0.70710678118654752f));  // exact GELU
  }
  __syncthreads();
  {
    int h = t >> 3, seg = t & 7;               // 32 heads x 8 segments
    float s = 0.f;
    const float* hp = hid_s + seg * 16;
    const float* wp = w2 + (seg * 16) * 32 + h;
#pragma unroll
    for (int m = 0; m < 16; m++) s = fmaf(hp[m], wp[m * 32], s);
    s += __shfl_xor(s, 1);
    s += __shfl_xor(s, 2);
    s += __shfl_xor(s, 4);
    if (seg == 0) tableG[h * (KN + 1) + g] = s + b2[h];
  }

  // ---- padding mask rows 8g..8g+7 ----
  if (g < 256) {
#pragma unroll
    for (int r = 0; r < 8; r++) {
      const float* p = nf + (size_t)(g * 8 + r) * 768;
      bool nz = (p[t] != 0.f) || (p[t + 256] != 0.f) || (p[t + 512] != 0.f);
      unsigned long long bal = __ballot(nz);
      if ((t & 63) == 0) wany[r][t >> 6] = (bal != 0ull);
    }
    __syncthreads();
    if (t < 8)
      mask[g * 8 + t] = (wany[t][0] | wany[t][1] | wany[t][2] | wany[t][3]) ? 0 : 1;
  }
}

// ---------------- kernel B1: grid 512. Block g: 4 query rows (global row = 4g+r).
// p_j loaded once per thread, reused over the 4 rows. Total wg 2048 -> 512.
__global__ __launch_bounds__(256) void e_kernel(
    const float* __restrict__ pos, const int* __restrict__ mask,
    float* __restrict__ ebuf, float* __restrict__ out2, float* __restrict__ part) {
  __shared__ float part_s[4][128];
  int t = threadIdx.x, g = blockIdx.x;
  int b = g >> 6;
  int row0 = g * 4;                            // global (b*256+i) of first row
  if (t < 128) {
    part_s[0][t] = 0.f; part_s[1][t] = 0.f; part_s[2][t] = 0.f; part_s[3][t] = 0.f;
  }
  __syncthreads();

  int j = t;
  const float* pb = pos + b * 768;
  float pjx = pb[j * 3 + 0], pjy = pb[j * 3 + 1], pjz = pb[j * 3 + 2];
  bool pad = mask[b * 256 + j] != 0;

  for (int r = 0; r < 4; r++) {
    int i = (g & 63) * 4 + r;
    float dx = pb[i * 3 + 0] - pjx;
    float dy = pb[i * 3 + 1] - pjy;
    float dz = pb[i * 3 + 2] - pjz;
    float r2 = dx * dx + dy * dy + dz * dz;
    float d = (r2 > 0.f) ? sqrtf(r2) : 0.f;
    float e = __expf(-d);                      // ALPHA=1, CUT_LO=0
    size_t base2 = ((size_t)(row0 + r) * 256 + (size_t)j) * 3;
    out2[base2 + 0] = dx; out2[base2 + 1] = dy; out2[base2 + 2] = dz;
    ebuf[(size_t)(row0 + r) * 256 + j] = e;
    if (!pad) {
      int kc = (int)rintf((e - RBF_START) * RBF_INVH);
      kc = min(max(kc, 0), 127);
      int kb = kc - 8;                         // exp(-beta*dk^2) < 8e-8 for |dk| >= 8
#pragma unroll
      for (int o = 0; o < 16; o++) {
        int k = kb + o;
        if (k >= 0 && k < 128) {
          float mu = fmaf((float)k, RBF_H, RBF_START);
          float diff = e - mu;
          atomicAdd(&part_s[r][k], __expf(-RBF_BETA * diff * diff));
        }
      }
    }
  }
  __syncthreads();
  if (t < 128) {
#pragma unroll
    for (int r = 0; r < 4; r++)
      part[(size_t)(row0 + r) * 128 + t] = part_s[r][t];
  }
}

// ---------------- kernel B2: grid 512 = (b, h, half). Wave w owns 32 contiguous rows
// (32 KB ascending stream). 2 blocks/CU x 4 waves = 8 waves/CU, unroll-4 ILP.
// Total wg 1024/2048 -> 512.
__global__ __launch_bounds__(256) void bias_kernel(
    const float* __restrict__ tableG, const int* __restrict__ mask,
    const float* __restrict__ ebuf, float* __restrict__ out0) {
  __shared__ f32x2 Tp[256];                    // Tp[k] = {T[k], T[k+1]}
  int t = threadIdx.x, g = blockIdx.x;
  int b = g >> 6, h = (g >> 1) & 31, half = g & 1;
  {
    float lo = tableG[h * (KN + 1) + t];
    float hi = tableG[h * (KN + 1) + t + 1];   // t+1 <= 256, in row
    Tp[t] = (f32x2){lo, hi};
  }
  int w = t >> 6, l = t & 63;
  i32x4 m4 = *(const i32x4*)&mask[b * 256 + l * 4];
  __syncthreads();

  int i0 = half * 128 + w * 32;                // this wave's first row
  const float* eb_ = ebuf + ((size_t)(b * 256 + i0)) * 256 + (size_t)(l * 4);
  float*       ob_ = out0 + ((size_t)((b * 32 + h) * 256 + i0)) * 256 + (size_t)(l * 4);

#pragma unroll 4
  for (int it = 0; it < 32; it++) {
    f32x4 e4 = *(const f32x4*)&eb_[(size_t)it * 256];
    f32x4 o;
#pragma unroll
    for (int q = 0; q < 4; q++) {
      float u = e4[q] * (float)KN;
      int iq = (int)u; iq = min(iq, KN - 1);
      float fr = u - (float)iq;
      f32x2 tp = Tp[iq];
      o[q] = m4[q] ? -1e20f : fmaf(fr, tp[1] - tp[0], tp[0]);
    }
    *(f32x4*)&ob_[(size_t)it * 256] = o;
  }
}

// ---------------- kernel C: grid 64, 4 reps of 8 rows. Total wg 256 -> 64.
__global__ __launch_bounds__(256) void merge_kernel(const float* __restrict__ part,
                                                    const float* __restrict__ ew,
                                                    const float* __restrict__ eb,
                                                    float* __restrict__ out1) {
  __shared__ float s_s[8][128];
  int t = threadIdx.x;
  for (int rep = 0; rep < 4; rep++) {
    int r0 = blockIdx.x * 32 + rep * 8;
    for (int idx = t; idx < 1024; idx += 256) {
      int row = idx >> 7, k = idx & 127;
      s_s[row][k] = part[(size_t)(r0 + row) * 128 + k];
    }
    __syncthreads();
    float acc[3][8];
#pragma unroll
    for (int c = 0; c < 3; c++)
#pragma unroll
      for (int r = 0; r < 8; r++) acc[c][r] = 0.f;
    for (int k = 0; k < 128; k++) {
      float w0 = ew[k * 768 + t];
      float w1v = ew[k * 768 + t + 256];
      float w2v = ew[k * 768 + t + 512];
#pragma unroll
      for (int r = 0; r < 8; r++) {
        float s = s_s[r][k];
        acc[0][r] += s * w0;
        acc[1][r] += s * w1v;
        acc[2][r] += s * w2v;
      }
    }
#pragma unroll
    for (int c = 0; c < 3; c++) {
      float ebv = eb[c * 256 + t];
#pragma unroll
      for (int r = 0; r < 8; r++)
        out1[(size_t)(r0 + r) * 768 + c * 256 + t] = acc[c][r] + ebv;
    }
    __syncthreads();                            // s_s reused next rep
  }
}

// ---------------- launch ----------------
extern "C" void kernel_launch(void* const* d_in, const int* in_sizes, int n_in,
                              void* d_out, int out_size, void* d_ws, size_t ws_size,
                              hipStream_t stream) {
    const float* nf    = (const float*)d_in[0];
    const float* pos   = (const float*)d_in[1];
    const float* w1    = (const float*)d_in[4];
    const float* b1    = (const float*)d_in[5];
    const float* w2    = (const float*)d_in[6];
    const float* b2    = (const float*)d_in[7];
    const float* ew    = (const float*)d_in[8];
    const float* eb    = (const float*)d_in[9];

    float* out0 = (float*)d_out;                         // [8,32,256,256]
    float* out1 = out0 + (size_t)8 * 32 * 256 * 256;     // [8,256,768]
    float* out2 = out1 + (size_t)8 * 256 * 768;          // [8,256,256,3]

    char* ws = (char*)d_ws;
    int*    mask   = (int*)ws;                           // 8 KB
    float*  tableG = (float*)(ws + 8192);                // 32896 B
    float*  part   = (float*)(ws + 49152);               // 2048*128*4 = 1 MB
    float*  ebuf   = (float*)(ws + 49152 + 1048576);     // 2048*256*4 = 2 MB

    hipLaunchKernelGGL(prep_kernel,  dim3(257), dim3(256), 0, stream,
                       nf, mask, w1, b1, w2, b2, tableG);
    hipLaunchKernelGGL(e_kernel,     dim3(512), dim3(256), 0, stream,
                       pos, mask, ebuf, out2, part);
    hipLaunchKernelGGL(bias_kernel,  dim3(512), dim3(256), 0, stream,
                       tableG, mask, ebuf, out0);
    hipLaunchKernelGGL(merge_kernel, dim3(64),  dim3(256), 0, stream, part, ew, eb, out1);
}

// Round 11
// 169.866 us; speedup vs baseline: 1.2437x; 1.2437x over previous
//
#include <hip/hip_runtime.h>
#include <math.h>

typedef float f32x4 __attribute__((ext_vector_type(4)));

// RBF constants: means = linspace(exp(-5), 1, 128); beta = (2/128*(1-exp(-5)))^-2
#define RBF_START 0.006737946999085467f
#define RBF_H     (0.993262053000915f / 127.0f)
#define RBF_INVH  (127.0f / 0.993262053000915f)
#define RBF_BETA  (1.0f / ((2.0f/128.0f*0.993262053000915f) * (2.0f/128.0f*0.993262053000915f)))
#define KN 256          // knots: KN+1 samples of e in [0,1]; lerp err ~1e-6 on bias

// ---------------- kernel A: grid 257. Block g: bias-table knot g (pair layout);
// blocks 0..255 also compute padding mask for rows 8g..8g+7.
// tableP[k][h] = {T[h][k], T[h][k+1]}, stored as floats tb[k*64 + h*2 + {0,1}], k in 0..255.
__global__ __launch_bounds__(256) void prep_kernel(
    const float* __restrict__ nf, int* __restrict__ mask,
    const float* __restrict__ w1, const float* __restrict__ b1,
    const float* __restrict__ w2, const float* __restrict__ b2,
    float* __restrict__ tb) {
  int g = blockIdx.x, t = threadIdx.x;
  __shared__ float ef_s[128];
  __shared__ float hid_s[128];
  __shared__ int wany[8][4];

  // ---- table knot g ----
  float e = (float)g * (1.0f / (float)KN);
  if (t < 128) {
    float mu = fmaf((float)t, RBF_H, RBF_START);
    float diff = e - mu;
    ef_s[t] = __expf(-RBF_BETA * diff * diff);
  }
  __syncthreads();
  if (t < 128) {
    float s = b1[t];
    for (int k = 0; k < 128; k++) s = fmaf(ef_s[k], w1[k * 128 + t], s);
    hid_s[t] = 0.5f * s * (1.0f + erff(s * 0.70710678118654752f));  // exact GELU
  }
  __syncthreads();
  {
    int h = t >> 3, seg = t & 7;               // 32 heads x 8 segments
    float s = 0.f;
    const float* hp = hid_s + seg * 16;
    const float* wp = w2 + (seg * 16) * 32 + h;
#pragma unroll
    for (int m = 0; m < 16; m++) s = fmaf(hp[m], wp[m * 32], s);
    s += __shfl_xor(s, 1);
    s += __shfl_xor(s, 2);
    s += __shfl_xor(s, 4);
    if (seg == 0) {
      float v = s + b2[h];                     // T[h][g]
      if (g < 256) tb[g * 64 + h * 2 + 0] = v;           // .x of row g
      if (g > 0)   tb[(g - 1) * 64 + h * 2 + 1] = v;     // .y of row g-1
    }
  }

  // ---- padding mask rows 8g..8g+7 ----
  if (g < 256) {
#pragma unroll
    for (int r = 0; r < 8; r++) {
      const float* p = nf + (size_t)(g * 8 + r) * 768;
      bool nz = (p[t] != 0.f) || (p[t + 256] != 0.f) || (p[t + 512] != 0.f);
      unsigned long long bal = __ballot(nz);
      if ((t & 63) == 0) wany[r][t >> 6] = (bal != 0ull);
    }
    __syncthreads();
    if (t < 8)
      mask[g * 8 + t] = (wany[t][0] | wany[t][1] | wany[t][2] | wany[t][3]) ? 0 : 1;
  }
}

// ---------------- kernel B: fused per-pair kernel, 2048 wg, 512 B LDS ----------------
// Block = one (b,i); thread t <-> j. No LDS table: each thread loads its OWN 256 B
// pair-row tableP[i0][:] (8x dwordx4, L2-hot) and does 32 register lerps.
// LDS = part_s only -> 8 blocks/CU (32 waves) vs previous 4 (16): occupancy x2.
__global__ __launch_bounds__(256) void main_kernel(
    const float* __restrict__ pos, const int* __restrict__ mask,
    const float* __restrict__ tb,
    float* __restrict__ out0, float* __restrict__ out2,
    float* __restrict__ part) {
  __shared__ float part_s[128];
  int t = threadIdx.x, g = blockIdx.x;
  int b = g >> 8, i = g & 255;
  if (t < 128) part_s[t] = 0.f;
  __syncthreads();

  // distance, e = exp(-d), delta_pos out
  int j = t;
  const float* pb = pos + b * 768;
  float dx = pb[i * 3 + 0] - pb[j * 3 + 0];
  float dy = pb[i * 3 + 1] - pb[j * 3 + 1];
  float dz = pb[i * 3 + 2] - pb[j * 3 + 2];
  float r2 = dx * dx + dy * dy + dz * dz;
  float d = (r2 > 0.f) ? sqrtf(r2) : 0.f;
  float e = __expf(-d);                        // ALPHA=1, CUT_LO=0
  size_t base2 = ((size_t)g * 256 + (size_t)j) * 3;
  out2[base2 + 0] = dx; out2[base2 + 1] = dy; out2[base2 + 2] = dz;

  bool pad = mask[b * 256 + j] != 0;

  // banded RBF -> LDS atomic column sums (exact exp path)
  if (!pad) {
    int kc = (int)rintf((e - RBF_START) * RBF_INVH);
    kc = min(max(kc, 0), 127);
    int kb = kc - 8;                           // exp(-beta*dk^2) < 8e-8 for |dk| >= 8
#pragma unroll
    for (int o = 0; o < 16; o++) {
      int k = kb + o;
      if (k >= 0 && k < 128) {
        float mu = fmaf((float)k, RBF_H, RBF_START);
        float diff = e - mu;
        atomicAdd(&part_s[k], __expf(-RBF_BETA * diff * diff));
      }
    }
  }

  // 32-head bias: one pair-row load + register lerps + scattered-by-h 256B stores
  {
    float u = e * (float)KN;
    int i0 = (int)u; i0 = min(i0, KN - 1);
    float fr = u - (float)i0;
    const f32x4* tp4 = (const f32x4*)(tb + (size_t)i0 * 64);
    size_t ob = (size_t)b * 2097152 + (size_t)i * 256 + (size_t)j;
#pragma unroll
    for (int r = 0; r < 8; r++) {
      f32x4 pr = tp4[r];                       // {T[2r].x, T[2r].y, T[2r+1].x, T[2r+1].y}
      float v0 = fmaf(fr, pr[1] - pr[0], pr[0]);
      float v1 = fmaf(fr, pr[3] - pr[2], pr[2]);
      out0[ob + (size_t)(2 * r) * 65536]     = pad ? -1e20f : v0;
      out0[ob + (size_t)(2 * r + 1) * 65536] = pad ? -1e20f : v1;
    }
  }

  __syncthreads();
  if (t < 128) part[(size_t)g * 128 + t] = part_s[t];
}

// ---------------- kernel C: merge_edge_features = part @ ew + eb (R1-proven, 256 wg) ----------------
__global__ __launch_bounds__(256) void merge_kernel(const float* __restrict__ part,
                                                    const float* __restrict__ ew,
                                                    const float* __restrict__ eb,
                                                    float* __restrict__ out1) {
  __shared__ float s_s[8][128];
  int t = threadIdx.x;
  int r0 = blockIdx.x * 8;
  for (int idx = t; idx < 1024; idx += 256) {
    int row = idx >> 7, k = idx & 127;
    s_s[row][k] = part[(size_t)(r0 + row) * 128 + k];
  }
  __syncthreads();
  float acc[3][8];
#pragma unroll
  for (int c = 0; c < 3; c++)
#pragma unroll
    for (int r = 0; r < 8; r++) acc[c][r] = 0.f;
  for (int k = 0; k < 128; k++) {
    float w0 = ew[k * 768 + t];
    float w1v = ew[k * 768 + t + 256];
    float w2v = ew[k * 768 + t + 512];
#pragma unroll
    for (int r = 0; r < 8; r++) {
      float s = s_s[r][k];
      acc[0][r] += s * w0;
      acc[1][r] += s * w1v;
      acc[2][r] += s * w2v;
    }
  }
#pragma unroll
  for (int c = 0; c < 3; c++) {
    float ebv = eb[c * 256 + t];
#pragma unroll
    for (int r = 0; r < 8; r++)
      out1[(size_t)(r0 + r) * 768 + c * 256 + t] = acc[c][r] + ebv;
  }
}

// ---------------- launch ----------------
extern "C" void kernel_launch(void* const* d_in, const int* in_sizes, int n_in,
                              void* d_out, int out_size, void* d_ws, size_t ws_size,
                              hipStream_t stream) {
    const float* nf    = (const float*)d_in[0];
    const float* pos   = (const float*)d_in[1];
    const float* w1    = (const float*)d_in[4];
    const float* b1    = (const float*)d_in[5];
    const float* w2    = (const float*)d_in[6];
    const float* b2    = (const float*)d_in[7];
    const float* ew    = (const float*)d_in[8];
    const float* eb    = (const float*)d_in[9];

    float* out0 = (float*)d_out;                         // [8,32,256,256]
    float* out1 = out0 + (size_t)8 * 32 * 256 * 256;     // [8,256,768]
    float* out2 = out1 + (size_t)8 * 256 * 768;          // [8,256,256,3]

    char* ws = (char*)d_ws;
    int*    mask   = (int*)ws;                           // 8 KB
    float*  tb     = (float*)(ws + 8192);                // pair table: 256*64*4 = 64 KB
    float*  part   = (float*)(ws + 81920);               // 2048*128*4 = 1 MB

    hipLaunchKernelGGL(prep_kernel,  dim3(257),  dim3(256), 0, stream,
                       nf, mask, w1, b1, w2, b2, tb);
    hipLaunchKernelGGL(main_kernel,  dim3(2048), dim3(256), 0, stream,
                       pos, mask, tb, out0, out2, part);
    hipLaunchKernelGGL(merge_kernel, dim3(256),  dim3(256), 0, stream, part, ew, eb, out1);
}

// Round 12
// 142.242 us; speedup vs baseline: 1.4852x; 1.1942x over previous
//
#include <hip/hip_runtime.h>
#include <math.h>

typedef float f32x4 __attribute__((ext_vector_type(4)));

// RBF constants: means = linspace(exp(-5), 1, 128); beta = (2/128*(1-exp(-5)))^-2
#define RBF_START 0.006737946999085467f
#define RBF_H     (0.993262053000915f / 127.0f)
#define RBF_INVH  (127.0f / 0.993262053000915f)
#define RBF_BETA  (1.0f / ((2.0f/128.0f*0.993262053000915f) * (2.0f/128.0f*0.993262053000915f)))
#define KN 256          // knots: KN+1 samples of e in [0,1]; lerp err ~1e-6 on bias

// ---------------- kernel A: grid 257. Block g: bias-table knot g (pair layout);
// blocks 0..255 also compute padding mask for rows 8g..8g+7.
// tableP[k][h] = {T[h][k], T[h][k+1]}, stored as floats tb[k*64 + h*2 + {0,1}], k in 0..255.
__global__ __launch_bounds__(256) void prep_kernel(
    const float* __restrict__ nf, int* __restrict__ mask,
    const float* __restrict__ w1, const float* __restrict__ b1,
    const float* __restrict__ w2, const float* __restrict__ b2,
    float* __restrict__ tb) {
  int g = blockIdx.x, t = threadIdx.x;
  __shared__ float ef_s[128];
  __shared__ float hid_s[128];
  __shared__ int wany[8][4];

  // ---- table knot g ----
  float e = (float)g * (1.0f / (float)KN);
  if (t < 128) {
    float mu = fmaf((float)t, RBF_H, RBF_START);
    float diff = e - mu;
    ef_s[t] = __expf(-RBF_BETA * diff * diff);
  }
  __syncthreads();
  if (t < 128) {
    float s = b1[t];
    for (int k = 0; k < 128; k++) s = fmaf(ef_s[k], w1[k * 128 + t], s);
    hid_s[t] = 0.5f * s * (1.0f + erff(s * 0.70710678118654752f));  // exact GELU
  }
  __syncthreads();
  {
    int h = t >> 3, seg = t & 7;               // 32 heads x 8 segments
    float s = 0.f;
    const float* hp = hid_s + seg * 16;
    const float* wp = w2 + (seg * 16) * 32 + h;
#pragma unroll
    for (int m = 0; m < 16; m++) s = fmaf(hp[m], wp[m * 32], s);
    s += __shfl_xor(s, 1);
    s += __shfl_xor(s, 2);
    s += __shfl_xor(s, 4);
    if (seg == 0) {
      float v = s + b2[h];                     // T[h][g]
      if (g < 256) tb[g * 64 + h * 2 + 0] = v;           // .x of row g
      if (g > 0)   tb[(g - 1) * 64 + h * 2 + 1] = v;     // .y of row g-1
    }
  }

  // ---- padding mask rows 8g..8g+7 ----
  if (g < 256) {
#pragma unroll
    for (int r = 0; r < 8; r++) {
      const float* p = nf + (size_t)(g * 8 + r) * 768;
      bool nz = (p[t] != 0.f) || (p[t + 256] != 0.f) || (p[t + 512] != 0.f);
      unsigned long long bal = __ballot(nz);
      if ((t & 63) == 0) wany[r][t >> 6] = (bal != 0ull);
    }
    __syncthreads();
    if (t < 8)
      mask[g * 8 + t] = (wany[t][0] | wany[t][1] | wany[t][2] | wany[t][3]) ? 0 : 1;
  }
}

// ---------------- kernel B: fused per-pair kernel, 2048 wg, ~2 KB LDS ----------------
// Block = one (b,i); thread t <-> j. Pair-table register lerps (R11-proven).
// NEW: column sums are ATOMIC-FREE: transpose the reduction. e_s[j] holds e (padded j ->
// sentinel 3.0 whose RBF term underflows to exactly 0); thread (k=t&127, half=t>>7)
// sweeps its 128 j's via broadcast f32x4 LDS reads, unconditional __expf (out-of-band
// underflows to 0 -- branchless, and MORE accurate than the old 16-wide band).
__global__ __launch_bounds__(256) void main_kernel(
    const float* __restrict__ pos, const int* __restrict__ mask,
    const float* __restrict__ tb,
    float* __restrict__ out0, float* __restrict__ out2,
    float* __restrict__ part) {
  __shared__ float e_s[256];
  __shared__ float ps[2][128];
  int t = threadIdx.x, g = blockIdx.x;
  int b = g >> 8, i = g & 255;

  // stage 1: distance, e = exp(-d), delta_pos out, e_s
  int j = t;
  const float* pb = pos + b * 768;
  float dx = pb[i * 3 + 0] - pb[j * 3 + 0];
  float dy = pb[i * 3 + 1] - pb[j * 3 + 1];
  float dz = pb[i * 3 + 2] - pb[j * 3 + 2];
  float r2 = dx * dx + dy * dy + dz * dz;
  float d = (r2 > 0.f) ? sqrtf(r2) : 0.f;
  float e = __expf(-d);                        // ALPHA=1, CUT_LO=0
  size_t base2 = ((size_t)g * 256 + (size_t)j) * 3;
  out2[base2 + 0] = dx; out2[base2 + 1] = dy; out2[base2 + 2] = dz;

  bool pad = mask[b * 256 + j] != 0;
  e_s[j] = pad ? 3.0f : e;                     // sentinel: beta*(3-mu)^2 > 1000 -> exp = 0

  // stage 2: 32-head bias, one pair-row load + register lerps (issue early; overlaps stage 3)
  {
    float u = e * (float)KN;
    int i0 = (int)u; i0 = min(i0, KN - 1);
    float fr = u - (float)i0;
    const f32x4* tp4 = (const f32x4*)(tb + (size_t)i0 * 64);
    size_t ob = (size_t)b * 2097152 + (size_t)i * 256 + (size_t)j;
#pragma unroll
    for (int r = 0; r < 8; r++) {
      f32x4 pr = tp4[r];                       // {T[2r].x, T[2r].y, T[2r+1].x, T[2r+1].y}
      float v0 = fmaf(fr, pr[1] - pr[0], pr[0]);
      float v1 = fmaf(fr, pr[3] - pr[2], pr[2]);
      out0[ob + (size_t)(2 * r) * 65536]     = pad ? -1e20f : v0;
      out0[ob + (size_t)(2 * r + 1) * 65536] = pad ? -1e20f : v1;
    }
  }

  // stage 3: atomic-free transposed column sums
  __syncthreads();                             // e_s ready
  {
    int k = t & 127, half = t >> 7;
    float mu = fmaf((float)k, RBF_H, RBF_START);
    float s = 0.f;
    const f32x4* ev = (const f32x4*)&e_s[half * 128];
#pragma unroll 8
    for (int q4 = 0; q4 < 32; q4++) {
      f32x4 e4 = ev[q4];                       // wave-uniform addr -> LDS broadcast
#pragma unroll
      for (int q = 0; q < 4; q++) {
        float df = e4[q] - mu;
        s += __expf(-RBF_BETA * df * df);      // out-of-band underflows to 0
      }
    }
    ps[half][k] = s;
  }
  __syncthreads();
  if (t < 128) part[(size_t)g * 128 + t] = ps[0][t] + ps[1][t];
}

// ---------------- kernel C: merge_edge_features = part @ ew + eb (R1-proven, 256 wg) ----------------
__global__ __launch_bounds__(256) void merge_kernel(const float* __restrict__ part,
                                                    const float* __restrict__ ew,
                                                    const float* __restrict__ eb,
                                                    float* __restrict__ out1) {
  __shared__ float s_s[8][128];
  int t = threadIdx.x;
  int r0 = blockIdx.x * 8;
  for (int idx = t; idx < 1024; idx += 256) {
    int row = idx >> 7, k = idx & 127;
    s_s[row][k] = part[(size_t)(r0 + row) * 128 + k];
  }
  __syncthreads();
  float acc[3][8];
#pragma unroll
  for (int c = 0; c < 3; c++)
#pragma unroll
    for (int r = 0; r < 8; r++) acc[c][r] = 0.f;
  for (int k = 0; k < 128; k++) {
    float w0 = ew[k * 768 + t];
    float w1v = ew[k * 768 + t + 256];
    float w2v = ew[k * 768 + t + 512];
#pragma unroll
    for (int r = 0; r < 8; r++) {
      float s = s_s[r][k];
      acc[0][r] += s * w0;
      acc[1][r] += s * w1v;
      acc[2][r] += s * w2v;
    }
  }
#pragma unroll
  for (int c = 0; c < 3; c++) {
    float ebv = eb[c * 256 + t];
#pragma unroll
    for (int r = 0; r < 8; r++)
      out1[(size_t)(r0 + r) * 768 + c * 256 + t] = acc[c][r] + ebv;
  }
}

// ---------------- launch ----------------
extern "C" void kernel_launch(void* const* d_in, const int* in_sizes, int n_in,
                              void* d_out, int out_size, void* d_ws, size_t ws_size,
                              hipStream_t stream) {
    const float* nf    = (const float*)d_in[0];
    const float* pos   = (const float*)d_in[1];
    const float* w1    = (const float*)d_in[4];
    const float* b1    = (const float*)d_in[5];
    const float* w2    = (const float*)d_in[6];
    const float* b2    = (const float*)d_in[7];
    const float* ew    = (const float*)d_in[8];
    const float* eb    = (const float*)d_in[9];

    float* out0 = (float*)d_out;                         // [8,32,256,256]
    float* out1 = out0 + (size_t)8 * 32 * 256 * 256;     // [8,256,768]
    float* out2 = out1 + (size_t)8 * 256 * 768;          // [8,256,256,3]

    char* ws = (char*)d_ws;
    int*    mask   = (int*)ws;                           // 8 KB
    float*  tb     = (float*)(ws + 8192);                // pair table: 256*64*4 = 64 KB
    float*  part   = (float*)(ws + 81920);               // 2048*128*4 = 1 MB

    hipLaunchKernelGGL(prep_kernel,  dim3(257),  dim3(256), 0, stream,
                       nf, mask, w1, b1, w2, b2, tb);
    hipLaunchKernelGGL(main_kernel,  dim3(2048), dim3(256), 0, stream,
                       pos, mask, tb, out0, out2, part);
    hipLaunchKernelGGL(merge_kernel, dim3(256),  dim3(256), 0, stream, part, ew, eb, out1);
}

// Round 13
// 136.890 us; speedup vs baseline: 1.5433x; 1.0391x over previous
//
#include <hip/hip_runtime.h>
#include <math.h>

typedef float f32x4 __attribute__((ext_vector_type(4)));

// RBF constants: means = linspace(exp(-5), 1, 128); beta = (2/128*(1-exp(-5)))^-2
#define RBF_START 0.006737946999085467f
#define RBF_H     (0.993262053000915f / 127.0f)
#define RBF_INVH  (127.0f / 0.993262053000915f)
#define RBF_BETA  (1.0f / ((2.0f/128.0f*0.993262053000915f) * (2.0f/128.0f*0.993262053000915f)))
#define KN 256          // knots: KN+1 samples of e in [0,1]; lerp err ~1e-6 on bias

// ---------------- kernel A: grid 257. Block g: bias-table knot g (pair layout);
// blocks 0..255 also compute padding mask for rows 8g..8g+7.
// tableP[k][h] = {T[h][k], T[h][k+1]}, stored as floats tb[k*64 + h*2 + {0,1}], k in 0..255.
__global__ __launch_bounds__(256) void prep_kernel(
    const float* __restrict__ nf, int* __restrict__ mask,
    const float* __restrict__ w1, const float* __restrict__ b1,
    const float* __restrict__ w2, const float* __restrict__ b2,
    float* __restrict__ tb) {
  int g = blockIdx.x, t = threadIdx.x;
  __shared__ float ef_s[128];
  __shared__ float hid_s[128];
  __shared__ int wany[8][4];

  // ---- table knot g ----
  float e = (float)g * (1.0f / (float)KN);
  if (t < 128) {
    float mu = fmaf((float)t, RBF_H, RBF_START);
    float diff = e - mu;
    ef_s[t] = __expf(-RBF_BETA * diff * diff);
  }
  __syncthreads();
  if (t < 128) {
    float s = b1[t];
    for (int k = 0; k < 128; k++) s = fmaf(ef_s[k], w1[k * 128 + t], s);
    hid_s[t] = 0.5f * s * (1.0f + erff(s * 0.70710678118654752f));  // exact GELU
  }
  __syncthreads();
  {
    int h = t >> 3, seg = t & 7;               // 32 heads x 8 segments
    float s = 0.f;
    const float* hp = hid_s + seg * 16;
    const float* wp = w2 + (seg * 16) * 32 + h;
#pragma unroll
    for (int m = 0; m < 16; m++) s = fmaf(hp[m], wp[m * 32], s);
    s += __shfl_xor(s, 1);
    s += __shfl_xor(s, 2);
    s += __shfl_xor(s, 4);
    if (seg == 0) {
      float v = s + b2[h];                     // T[h][g]
      if (g < 256) tb[g * 64 + h * 2 + 0] = v;           // .x of row g
      if (g > 0)   tb[(g - 1) * 64 + h * 2 + 1] = v;     // .y of row g-1
    }
  }

  // ---- padding mask rows 8g..8g+7 ----
  if (g < 256) {
#pragma unroll
    for (int r = 0; r < 8; r++) {
      const float* p = nf + (size_t)(g * 8 + r) * 768;
      bool nz = (p[t] != 0.f) || (p[t + 256] != 0.f) || (p[t + 512] != 0.f);
      unsigned long long bal = __ballot(nz);
      if ((t & 63) == 0) wany[r][t >> 6] = (bal != 0ull);
    }
    __syncthreads();
    if (t < 8)
      mask[g * 8 + t] = (wany[t][0] | wany[t][1] | wany[t][2] | wany[t][3]) ? 0 : 1;
  }
}

// ---------------- kernel B: fused per-pair kernel, 2048 wg, ~2 KB LDS (R12-proven) ----------------
__global__ __launch_bounds__(256) void main_kernel(
    const float* __restrict__ pos, const int* __restrict__ mask,
    const float* __restrict__ tb,
    float* __restrict__ out0, float* __restrict__ out2,
    float* __restrict__ part) {
  __shared__ float e_s[256];
  __shared__ float ps[2][128];
  int t = threadIdx.x, g = blockIdx.x;
  int b = g >> 8, i = g & 255;

  // stage 1: distance, e = exp(-d), delta_pos out, e_s
  int j = t;
  const float* pb = pos + b * 768;
  float dx = pb[i * 3 + 0] - pb[j * 3 + 0];
  float dy = pb[i * 3 + 1] - pb[j * 3 + 1];
  float dz = pb[i * 3 + 2] - pb[j * 3 + 2];
  float r2 = dx * dx + dy * dy + dz * dz;
  float d = (r2 > 0.f) ? sqrtf(r2) : 0.f;
  float e = __expf(-d);                        // ALPHA=1, CUT_LO=0
  size_t base2 = ((size_t)g * 256 + (size_t)j) * 3;
  out2[base2 + 0] = dx; out2[base2 + 1] = dy; out2[base2 + 2] = dz;

  bool pad = mask[b * 256 + j] != 0;
  e_s[j] = pad ? 3.0f : e;                     // sentinel: beta*(3-mu)^2 > 1000 -> exp = 0

  // stage 2: 32-head bias, one pair-row load + register lerps
  {
    float u = e * (float)KN;
    int i0 = (int)u; i0 = min(i0, KN - 1);
    float fr = u - (float)i0;
    const f32x4* tp4 = (const f32x4*)(tb + (size_t)i0 * 64);
    size_t ob = (size_t)b * 2097152 + (size_t)i * 256 + (size_t)j;
#pragma unroll
    for (int r = 0; r < 8; r++) {
      f32x4 pr = tp4[r];                       // {T[2r].x, T[2r].y, T[2r+1].x, T[2r+1].y}
      float v0 = fmaf(fr, pr[1] - pr[0], pr[0]);
      float v1 = fmaf(fr, pr[3] - pr[2], pr[2]);
      out0[ob + (size_t)(2 * r) * 65536]     = pad ? -1e20f : v0;
      out0[ob + (size_t)(2 * r + 1) * 65536] = pad ? -1e20f : v1;
    }
  }

  // stage 3: atomic-free transposed column sums
  __syncthreads();                             // e_s ready
  {
    int k = t & 127, half = t >> 7;
    float mu = fmaf((float)k, RBF_H, RBF_START);
    float s = 0.f;
    const f32x4* ev = (const f32x4*)&e_s[half * 128];
#pragma unroll 8
    for (int q4 = 0; q4 < 32; q4++) {
      f32x4 e4 = ev[q4];                       // wave-uniform addr -> LDS broadcast
#pragma unroll
      for (int q = 0; q < 4; q++) {
        float df = e4[q] - mu;
        s += __expf(-RBF_BETA * df * df);      // out-of-band underflows to 0
      }
    }
    ps[half][k] = s;
  }
  __syncthreads();
  if (t < 128) part[(size_t)g * 128 + t] = ps[0][t] + ps[1][t];
}

// ---------------- kernel C: merge = part @ ew + eb. 1024-thr blocks: 16 waves/CU
// (4/SIMD) instead of R1's 4 (1/SIMD) -- hides the k-loop's L2 load latency.
// Thread (q = t>>8, o = t&255) computes rows q*2..q*2+1, columns {o, o+256, o+512}.
// Same FMA total; ew address-duplicates across q served by L1 broadcast.
__global__ __launch_bounds__(1024) void merge_kernel(const float* __restrict__ part,
                                                     const float* __restrict__ ew,
                                                     const float* __restrict__ eb,
                                                     float* __restrict__ out1) {
  __shared__ float s_s[8][128];
  int t = threadIdx.x;
  int r0 = blockIdx.x * 8;
  {
    int row = t >> 7, k = t & 127;             // 1024 = 8*128: one load each
    s_s[row][k] = part[(size_t)(r0 + row) * 128 + k];
  }
  __syncthreads();

  int q = t >> 8, o = t & 255;
  float acc[3][2];
#pragma unroll
  for (int c = 0; c < 3; c++) { acc[c][0] = 0.f; acc[c][1] = 0.f; }

#pragma unroll 4
  for (int k = 0; k < 128; k++) {
    float w0 = ew[k * 768 + o];
    float w1v = ew[k * 768 + 256 + o];
    float w2v = ew[k * 768 + 512 + o];
    float s0 = s_s[q * 2 + 0][k];              // wave-uniform -> LDS broadcast
    float s1 = s_s[q * 2 + 1][k];
    acc[0][0] = fmaf(s0, w0, acc[0][0]);  acc[0][1] = fmaf(s1, w0, acc[0][1]);
    acc[1][0] = fmaf(s0, w1v, acc[1][0]); acc[1][1] = fmaf(s1, w1v, acc[1][1]);
    acc[2][0] = fmaf(s0, w2v, acc[2][0]); acc[2][1] = fmaf(s1, w2v, acc[2][1]);
  }

#pragma unroll
  for (int c = 0; c < 3; c++) {
    float ebv = eb[c * 256 + o];
#pragma unroll
    for (int r2 = 0; r2 < 2; r2++)
      out1[(size_t)(r0 + q * 2 + r2) * 768 + c * 256 + o] = acc[c][r2] + ebv;
  }
}

// ---------------- launch ----------------
extern "C" void kernel_launch(void* const* d_in, const int* in_sizes, int n_in,
                              void* d_out, int out_size, void* d_ws, size_t ws_size,
                              hipStream_t stream) {
    const float* nf    = (const float*)d_in[0];
    const float* pos   = (const float*)d_in[1];
    const float* w1    = (const float*)d_in[4];
    const float* b1    = (const float*)d_in[5];
    const float* w2    = (const float*)d_in[6];
    const float* b2    = (const float*)d_in[7];
    const float* ew    = (const float*)d_in[8];
    const float* eb    = (const float*)d_in[9];

    float* out0 = (float*)d_out;                         // [8,32,256,256]
    float* out1 = out0 + (size_t)8 * 32 * 256 * 256;     // [8,256,768]
    float* out2 = out1 + (size_t)8 * 256 * 768;          // [8,256,256,3]

    char* ws = (char*)d_ws;
    int*    mask   = (int*)ws;                           // 8 KB
    float*  tb     = (float*)(ws + 8192);                // pair table: 256*64*4 = 64 KB
    float*  part   = (float*)(ws + 81920);               // 2048*128*4 = 1 MB

    hipLaunchKernelGGL(prep_kernel,  dim3(257),  dim3(256), 0, stream,
                       nf, mask, w1, b1, w2, b2, tb);
    hipLaunchKernelGGL(main_kernel,  dim3(2048), dim3(256), 0, stream,
                       pos, mask, tb, out0, out2, part);
    hipLaunchKernelGGL(merge_kernel, dim3(256),  dim3(1024), 0, stream, part, ew, eb, out1);
}